// Round 12
// baseline (305.372 us; speedup 1.0000x reference)
//
#include <hip/hip_runtime.h>
#include <hip/hip_bf16.h>

// ---------------------------------------------------------------------------
// LinearAttentionBlock: Q=phi(xWq+bq), K=phi(xWk+bk), V=xWv+bv
// scores = tril(Q K^T); out = ((scores V) / (rowsum+eps)) Wo + bo
// Algebra (r11+r12):  W2 = V Wo = x(WvWo) + bvWo ;  out = (tril(S) W2)/d + bo
//   r12: Wfuse = Wv Wo (4.3 GF) + bfuse = bv Wo precomputed; W2 = x Wfuse +
//   bfuse (17 GF) replaces proj_v + vw (69 GF) and kills the V intermediate.
// Score path (QK-proj, QK^T): fp8 e4m3 via v_mfma_f32_16x16x128_f8f6f4.
// bf16 GEMMs: 16x16x32 core, 2-phase 128x128 tile, swizzled LDS.
// ---------------------------------------------------------------------------

#define D_MODEL 1024
#define D_INNER 2048
#define SEQ     2048
#define NBATCH  4
#define MTOT    (NBATCH * SEQ)   // 8192

typedef __attribute__((ext_vector_type(8))) __bf16 bf16x8;
typedef __attribute__((ext_vector_type(4))) float  f32x4;
typedef __attribute__((ext_vector_type(8))) short  short8v;
typedef __attribute__((ext_vector_type(4))) int    int4v;
typedef __attribute__((ext_vector_type(8))) int    int8v;

__device__ __forceinline__ short f2bf(float f) {      // RNE f32 -> bf16 bits
  union { float f; unsigned u; } x; x.f = f;
  unsigned r = x.u + 0x7fffu + ((x.u >> 16) & 1u);
  return (short)(r >> 16);
}
__device__ __forceinline__ float bf2f(short s) {
  union { unsigned u; float f; } x; x.u = ((unsigned)(unsigned short)s) << 16;
  return x.f;
}

// RNE f32 -> OCP e4m3fn (saturate to 448).
__device__ __forceinline__ unsigned char f2fp8(float f) {
  union { float f; unsigned u; } x; x.f = f;
  const unsigned s = (x.u >> 24) & 0x80u;
  const unsigned a = x.u & 0x7fffffffu;
  if (a >= 0x43E00000u) return (unsigned char)(s | 0x7Eu);   // >= 448 -> sat
  if (a < 0x3C800000u) {                                     // < 2^-6: subnormal
    union { float f; unsigned u; } y; y.u = a;
    const int mi = (int)rintf(y.f * 512.0f);                 // RNE, 0..8
    return (unsigned char)(s | (unsigned)mi);                // mi==8 -> 0x08 = 2^-6
  }
  const unsigned r = a + 0x7FFFFu + ((a >> 20) & 1u);        // RNE at 20 bits
  const unsigned E = (r >> 23) - 120u;                       // e4m3 exp field
  return (unsigned char)(s | (E << 3) | ((r >> 20) & 7u));
}

typedef const void __attribute__((address_space(1)))* as1cv;
typedef void __attribute__((address_space(3)))* as3v;

__device__ __forceinline__ void gload_lds16(const void* g, void* l) {
  __builtin_amdgcn_global_load_lds((as1cv)g, (as3v)l, 16, 0, 0);
}

__device__ __forceinline__ f32x4 mfma16(bf16x8 a, bf16x8 b, f32x4 c) {
  return __builtin_amdgcn_mfma_f32_16x16x32_bf16(a, b, c, 0, 0, 0);
}

// fp8 e4m3 x e4m3, K=128 (non-scaled f8f6f4; cbsz/blgp default 0 = fp8,fp8)
__device__ __forceinline__ f32x4 mfma_fp8(int8v a, int8v b, f32x4 c) {
  asm("v_mfma_f32_16x16x128_f8f6f4 %0, %1, %2, %0"
      : "+v"(c) : "v"(a), "v"(b));
  return c;
}

// ====================== bf16 GEMM core (16x16x32) ==========================
// LDS tile [128 rows][32 cols] bf16, 64B rows; slot ^= (row>>1)&3 swizzle.
__device__ __forceinline__ void gemm_pipe(const short* __restrict__ A, int lda, int aRowBase,
                                          const short* __restrict__ B, int ldb, int bRowBase,
                                          int k0, int k1, short* smem, f32x4 acc[4][4]) {
  const int t    = threadIdx.x;
  const int lane = t & 63, wid = t >> 6;
  const int wr = wid >> 1, wc = wid & 1;
  const int lrow = lane & 15, kblk = lane >> 4;

  const int r0 = t >> 2;
  const int sc = ((t & 3) ^ ((t >> 3) & 3)) * 8;      // pre-swizzled col
  const short* pA = A + (size_t)(aRowBase + r0) * lda + (k0 + sc);
  const short* pB = B + (size_t)(bRowBase + r0) * ldb + (k0 + sc);
  const size_t rA = (size_t)64 * lda;
  const size_t rB = (size_t)64 * ldb;

  int aoff[4], boff[4];
#pragma unroll
  for (int m = 0; m < 4; ++m) {
    const int row = wr * 64 + m * 16 + lrow;
    aoff[m] = (row * 64 + kblk * 16) ^ (((row >> 1) & 3) << 4);
  }
#pragma unroll
  for (int n = 0; n < 4; ++n) {
    const int row = wc * 64 + n * 16 + lrow;
    boff[n] = (row * 64 + kblk * 16) ^ (((row >> 1) & 3) << 4);
  }
  const char* cs = (const char*)smem;

#define STG(bufShorts) do {                                                    \
    gload_lds16(pA, smem + (bufShorts) + t * 8);                               \
    gload_lds16(pA + rA, smem + (bufShorts) + 2048 + t * 8);                   \
    gload_lds16(pB, smem + (bufShorts) + 4096 + t * 8);                        \
    gload_lds16(pB + rB, smem + (bufShorts) + 6144 + t * 8);                   \
    pA += 32; pB += 32;                                                        \
  } while (0)

#define CSTEP(bufBytes) do {                                                   \
    bf16x8 a[4], b[4];                                                         \
    _Pragma("unroll") for (int m = 0; m < 4; ++m)                              \
      a[m] = *(const bf16x8*)(cs + (bufBytes) + aoff[m]);                      \
    _Pragma("unroll") for (int n = 0; n < 4; ++n)                              \
      b[n] = *(const bf16x8*)(cs + (bufBytes) + 8192 + boff[n]);               \
    _Pragma("unroll") for (int m = 0; m < 4; ++m)                              \
      _Pragma("unroll") for (int n = 0; n < 4; ++n)                            \
        acc[m][n] = mfma16(a[m], b[n], acc[m][n]);                             \
  } while (0)

  STG(0);
  __syncthreads();
  for (int k = k0; k < k1; k += 64) {
    if (k + 32 < k1) STG(8192);
    CSTEP(0);
    __syncthreads();
    if (k + 64 < k1) STG(0);
    CSTEP(16384);
    __syncthreads();
  }
#undef STG
#undef CSTEP
}

// ============================ fp8 GEMM core ================================
// A[M,K] row-major fp8, B[N,K] row-major fp8; (k1-k0) multiple of 256.
// LDS tile [128 rows][128 B], 8 x 16B slots/row; slot ^= row&7 swizzle.
// Buffers: A0@0 B0@16K A1@32K B1@48K (64 KB total).
__device__ __forceinline__ void gemm_pipe8(const unsigned char* __restrict__ A, int lda, int aRowBase,
                                           const unsigned char* __restrict__ B, int ldb, int bRowBase,
                                           int k0, int k1, char* smem, f32x4 acc[4][4]) {
  const int t    = threadIdx.x;
  const int lane = t & 63, wid = t >> 6;
  const int wr = wid >> 1, wc = wid & 1;
  const int lrow = lane & 15, kblk = lane >> 4;

  const int srow = t >> 3;                              // 0..31
  const int scol = (((t & 7) ^ ((t >> 3) & 7)) << 4);   // pre-swizzled byte col
  const unsigned char* pA = A + (size_t)(aRowBase + srow) * lda + (k0 + scol);
  const unsigned char* pB = B + (size_t)(bRowBase + srow) * ldb + (k0 + scol);

  int aoff[4][2], boff[4][2];
#pragma unroll
  for (int m = 0; m < 4; ++m) {
    const int row = wr * 64 + m * 16 + lrow;
#pragma unroll
    for (int j = 0; j < 2; ++j)
      aoff[m][j] = row * 128 + (((kblk * 2 + j) ^ (row & 7)) << 4);
  }
#pragma unroll
  for (int n = 0; n < 4; ++n) {
    const int row = wc * 64 + n * 16 + lrow;
#pragma unroll
    for (int j = 0; j < 2; ++j)
      boff[n][j] = row * 128 + (((kblk * 2 + j) ^ (row & 7)) << 4);
  }

#define STG8(bufB) do {                                                        \
    _Pragma("unroll") for (int i = 0; i < 4; ++i) {                            \
      gload_lds16(pA + (size_t)(32 * i) * lda, smem + (bufB) + i * 4096 + t * 16);      \
      gload_lds16(pB + (size_t)(32 * i) * ldb, smem + (bufB) + 16384 + i * 4096 + t * 16); \
    }                                                                          \
    pA += 128; pB += 128;                                                      \
  } while (0)

#define CSTEP8(bufB) do {                                                      \
    int8v a[4], b[4];                                                          \
    _Pragma("unroll") for (int m = 0; m < 4; ++m)                              \
      _Pragma("unroll") for (int j = 0; j < 2; ++j)                            \
        ((int4v*)&a[m])[j] = *(const int4v*)(smem + (bufB) + aoff[m][j]);      \
    _Pragma("unroll") for (int n = 0; n < 4; ++n)                              \
      _Pragma("unroll") for (int j = 0; j < 2; ++j)                            \
        ((int4v*)&b[n])[j] = *(const int4v*)(smem + (bufB) + 16384 + boff[n][j]); \
    _Pragma("unroll") for (int m = 0; m < 4; ++m)                              \
      _Pragma("unroll") for (int n = 0; n < 4; ++n)                            \
        acc[m][n] = mfma_fp8(a[m], b[n], acc[m][n]);                           \
  } while (0)

  STG8(0);
  __syncthreads();
  for (int k = k0; k < k1; k += 256) {
    if (k + 128 < k1) STG8(32768);
    CSTEP8(0);
    __syncthreads();
    if (k + 256 < k1) STG8(0);
    CSTEP8(32768);
    __syncthreads();
  }
#undef STG8
#undef CSTEP8
}

#define GEMM_PRE                                           \
  __shared__ __align__(16) short smem[4 * 4096];           \
  f32x4 acc[4][4];                                         \
  _Pragma("unroll")                                        \
  for (int m = 0; m < 4; ++m)                              \
    _Pragma("unroll")                                      \
    for (int n = 0; n < 4; ++n) acc[m][n] = (f32x4){0.f, 0.f, 0.f, 0.f};

#define GEMM_PRE8                                          \
  __shared__ __align__(16) char smem8[65536];              \
  f32x4 acc[4][4];                                         \
  _Pragma("unroll")                                        \
  for (int m = 0; m < 4; ++m)                              \
    _Pragma("unroll")                                      \
    for (int n = 0; n < 4; ++n) acc[m][n] = (f32x4){0.f, 0.f, 0.f, 0.f};

#define EPILOG_VARS                                        \
  const int lane = threadIdx.x & 63;                       \
  const int wid  = threadIdx.x >> 6;                       \
  const int wr = wid >> 1, wc = wid & 1;                   \
  const int lrow = lane & 15, kblk = lane >> 4;

// Shared epilogue helper: transpose 128x128 bf16 tile through swizzled LDS
// (physical byte = cl*256 + ((rl*2)^((cl&7)<<5))), then 16B-coalesced stores
// to dst[(rowBase+er)*ldd + colBase + hf*64 .. +128).  Caller must have
// written the tile into smem and __syncthreads()'d.
__device__ __forceinline__ void retile_store(const short* smem, short* dst0, int ldd) {
  const int er  = threadIdx.x >> 1;                 // transposed-row 0..127
  const int hf  = threadIdx.x & 1;
  short* dst = dst0 + (size_t)er * ldd + hf * 64;
#pragma unroll
  for (int i = 0; i < 8; ++i) {                     // 8 x 16B = 64 elems
    int byte = er * 256 + hf * 128 + i * 16;
    byte ^= (er & 7) << 5;
    ((short8v*)dst)[i] = *(const short8v*)((const char*)smem + byte);
  }
}

// ---- fp8 Q/K projection: N = 4096 (Q | K), phi epilogue, fp8 out ----------
__global__ __launch_bounds__(256) void k_proj_qk8(const unsigned char* __restrict__ X8,
                                                  const unsigned char* __restrict__ WT8,
                                                  const float* __restrict__ bq,
                                                  const float* __restrict__ bk,
                                                  unsigned char* __restrict__ Qm8,
                                                  unsigned char* __restrict__ Km8) {
  GEMM_PRE8
  const int blockM = blockIdx.y * 128;
  const int blockN = blockIdx.x * 128;     // [0, 4096)
  gemm_pipe8(X8, D_MODEL, blockM, WT8, D_MODEL, blockN, 0, D_MODEL, smem8, acc);
  EPILOG_VARS
  const int seg = blockN >> 11;            // 0=Q 1=K
  const float* bias = (seg == 0) ? bq : bk;
  unsigned char* dst = (seg == 0) ? Qm8 : Km8;
#pragma unroll
  for (int m = 0; m < 4; ++m)
#pragma unroll
    for (int n = 0; n < 4; ++n) {
      const int e = (blockN & 2047) + wc * 64 + n * 16 + lrow;
      const float bvv = bias[e];
#pragma unroll
      for (int j = 0; j < 4; ++j) {
        const int row = blockM + wr * 64 + m * 16 + kblk * 4 + j;  // token
        float v = acc[m][n][j] + bvv;
        v = (v > 0.f) ? (v + 1.f) : __expf(v);      // elu(x)+1
        dst[(size_t)row * D_INNER + e] = f2fp8(v);
      }
    }
}

// ---- Wfuse = Wv Wo, written transposed: wfT[o][m], no bias ----------------
__global__ __launch_bounds__(256) void k_wfuse(const short* __restrict__ WvB,
                                               const short* __restrict__ WoT,
                                               short* __restrict__ wfT) {
  GEMM_PRE
  const int blockM = blockIdx.y * 128;     // m (d_model row of Wv)
  const int blockN = blockIdx.x * 128;     // o
  gemm_pipe(WvB, D_INNER, blockM, WoT, D_INNER, blockN, 0, D_INNER, smem, acc);
  EPILOG_VARS
#pragma unroll
  for (int m = 0; m < 4; ++m)
#pragma unroll
    for (int n = 0; n < 4; ++n) {
      const int cl = wc * 64 + n * 16 + lrow;       // o-local
#pragma unroll
      for (int j = 0; j < 4; ++j) {
        const int rl = wr * 64 + m * 16 + kblk * 4 + j;  // m-local
        int byte = cl * 256 + rl * 2;
        byte ^= (cl & 7) << 5;
        *(short*)((char*)smem + byte) = f2bf(acc[m][n][j]);
      }
    }
  __syncthreads();
  retile_store(smem, wfT + (size_t)blockN * D_MODEL + blockM, D_MODEL);
}

// ---- bfuse[o] = sum_e bv[e] * Wo[e][o]  (f32, exact-ish) ------------------
__global__ __launch_bounds__(256) void k_bfuse(const float* __restrict__ bv,
                                               const float* __restrict__ Wo,
                                               float* __restrict__ bfuse) {
  const int o = blockIdx.x * 256 + threadIdx.x;     // 0..1023
  float s = 0.f;
  for (int e = 0; e < D_INNER; ++e)
    s += bv[e] * Wo[(size_t)e * D_MODEL + o];
  bfuse[o] = s;
}

// ---- W2 = x Wfuse + bfuse, written transposed per batch: w2T[b][o][m] -----
__global__ __launch_bounds__(256) void k_w2(const short* __restrict__ X,
                                            const short* __restrict__ WfT,
                                            const float* __restrict__ bfuse,
                                            short* __restrict__ w2T) {
  GEMM_PRE
  const int blockM = blockIdx.y * 128;     // token (global)
  const int blockN = blockIdx.x * 128;     // o in [0, 1024)
  gemm_pipe(X, D_MODEL, blockM, WfT, D_MODEL, blockN, 0, D_MODEL, smem, acc);
  EPILOG_VARS
#pragma unroll
  for (int m = 0; m < 4; ++m)
#pragma unroll
    for (int n = 0; n < 4; ++n) {
      const int cl = wc * 64 + n * 16 + lrow;       // o-local
      const float bvv = bfuse[blockN + cl];
#pragma unroll
      for (int j = 0; j < 4; ++j) {
        const int rl = wr * 64 + m * 16 + kblk * 4 + j;  // token-local
        int byte = cl * 256 + rl * 2;
        byte ^= (cl & 7) << 5;
        *(short*)((char*)smem + byte) = f2bf(acc[m][n][j] + bvv);
      }
    }
  __syncthreads();
  const int b   = blockM >> 11;                     // batch
  const int mm0 = blockM & 2047;                    // token base in batch
  retile_store(smem, w2T + ((size_t)b * D_MODEL + blockN) * SEQ + mm0, SEQ);
}

// ---- scores = tril(Q K^T) in fp8, bf16 S out + row-sum partials -----------
__global__ __launch_bounds__(256) void k_qkt8(const unsigned char* __restrict__ Q8,
                                              const unsigned char* __restrict__ K8,
                                              short* __restrict__ S,
                                              float* __restrict__ den_part) {
  const int b = blockIdx.y;
  const int t = blockIdx.x;                // 0..135 -> (ib, jb<=ib)
  int ib = (int)((-1.0f + sqrtf(8.0f * (float)t + 1.0f)) * 0.5f);
  while ((ib + 1) * (ib + 2) / 2 <= t) ++ib;
  while (ib * (ib + 1) / 2 > t) --ib;
  const int jb = t - ib * (ib + 1) / 2;
  GEMM_PRE8
  short* Sb = S + (size_t)b * SEQ * SEQ;
  gemm_pipe8(Q8 + (size_t)b * SEQ * D_INNER, D_INNER, ib * 128,
             K8 + (size_t)b * SEQ * D_INNER, D_INNER, jb * 128,
             0, D_INNER, smem8, acc);
  EPILOG_VARS
  const bool diag = (jb == ib);
  float sums[4][4];
#pragma unroll
  for (int m = 0; m < 4; ++m)
#pragma unroll
    for (int j = 0; j < 4; ++j) sums[m][j] = 0.f;
#pragma unroll
  for (int m = 0; m < 4; ++m)
#pragma unroll
    for (int n = 0; n < 4; ++n) {
      const int col = jb * 128 + wc * 64 + n * 16 + lrow;       // j
#pragma unroll
      for (int j = 0; j < 4; ++j) {
        const int row = ib * 128 + wr * 64 + m * 16 + kblk * 4 + j;  // i
        float v = acc[m][n][j];
        if (diag && col > row) v = 0.f;
        const short bs = f2bf(v);
        Sb[(size_t)row * SEQ + col] = bs;
        sums[m][j] += bf2f(bs);            // sum what we stored (consistency)
      }
    }
#pragma unroll
  for (int m = 0; m < 4; ++m)
#pragma unroll
    for (int j = 0; j < 4; ++j) {
      float red = sums[m][j];
      red += __shfl_xor(red, 1, 64);
      red += __shfl_xor(red, 2, 64);
      red += __shfl_xor(red, 4, 64);
      red += __shfl_xor(red, 8, 64);
      if (lrow == 0) {
        const int rloc = wr * 64 + m * 16 + kblk * 4 + j;
        den_part[(size_t)(2 * jb + wc) * MTOT + b * SEQ + ib * 128 + rloc] = red;
      }
    }
}

// ---- out = (tril(S) W2)/d + bo  (fp32 out); K truncated; heavy ib first ---
__global__ __launch_bounds__(256) void k_sv(const short* __restrict__ S,
                                            const short* __restrict__ W2T,
                                            const float* __restrict__ den_part,
                                            const float* __restrict__ bo,
                                            float* __restrict__ out) {
  const int b = blockIdx.z;
  const int ib = 15 - blockIdx.y;          // heavy blocks dispatched first
  const int eb = blockIdx.x;               // o-tile 0..7
  __shared__ float dnm[128];
  {
    const int t = threadIdx.x;
    if (t < 128) {
      float s = 1e-6f;
      const int nv = 2 * (ib + 1);
      const float* dp = den_part + b * SEQ + ib * 128 + t;
      for (int q = 0; q < nv; ++q) s += dp[(size_t)q * MTOT];
      dnm[t] = 1.0f / s;
    }
  }
  GEMM_PRE
  gemm_pipe(S + (size_t)b * SEQ * SEQ, SEQ, ib * 128,
            W2T + (size_t)b * (size_t)D_MODEL * SEQ, SEQ, eb * 128,
            0, (ib + 1) * 128, smem, acc);  // internal barriers order dnm too
  EPILOG_VARS
  const int blockM = ib * 128;
#pragma unroll
  for (int m = 0; m < 4; ++m)
#pragma unroll
    for (int j = 0; j < 4; ++j) {
      const int rloc = wr * 64 + m * 16 + kblk * 4 + j;
      const int row = blockM + rloc;                 // token in batch
      const float rcp = dnm[rloc];
#pragma unroll
      for (int n = 0; n < 4; ++n) {
        const int col = eb * 128 + wc * 64 + n * 16 + lrow;      // o
        out[((size_t)(b * SEQ + row)) * D_MODEL + col] = acc[m][n][j] * rcp + bo[col];
      }
    }
}

// ---- converts: x -> bf16 (W2 path) + fp8 (score path) ---------------------
__global__ void k_cvt(const float* __restrict__ in, short* __restrict__ outb,
                      unsigned char* __restrict__ out8, int n4) {
  int i = blockIdx.x * blockDim.x + threadIdx.x;
  const int stride = gridDim.x * blockDim.x;
  for (; i < n4; i += stride) {
    float4 v = ((const float4*)in)[i];
    short4 o;
    o.x = f2bf(v.x); o.y = f2bf(v.y); o.z = f2bf(v.z); o.w = f2bf(v.w);
    ((short4*)outb)[i] = o;
    uchar4 q;
    q.x = f2fp8(v.x); q.y = f2fp8(v.y); q.z = f2fp8(v.z); q.w = f2fp8(v.w);
    ((uchar4*)out8)[i] = q;
  }
}

// weight prep in one launch:
// z=0,1: Wq/Wk [1024][2048] -> fp8 TRANSPOSED [2048][1024] into wqkT8
// z=2:   Wv    [1024][2048] -> bf16 same-layout convert (WvB, A-operand)
// z=3:   Wo    [2048][1024] -> bf16 TRANSPOSED [1024][2048] (woT)
__global__ __launch_bounds__(256) void k_transposeAll(const float* __restrict__ w0,
                                                      const float* __restrict__ w1,
                                                      const float* __restrict__ w2,
                                                      const float* __restrict__ w3,
                                                      unsigned char* __restrict__ wqkT8,
                                                      short* __restrict__ wvB,
                                                      short* __restrict__ woT) {
  __shared__ float tl[32][33];
  const int z = blockIdx.z;
  const float* in = (z == 0) ? w0 : (z == 1) ? w1 : (z == 2) ? w2 : w3;
  const int R = (z < 3) ? 1024 : 2048;     // in rows
  const int C = (z < 3) ? 2048 : 1024;     // in cols
  const int nbx = C >> 5;
  const int c0 = (blockIdx.x % nbx) * 32, r0 = (blockIdx.x / nbx) * 32;
  const int tx = threadIdx.x & 31, ty = (threadIdx.x >> 5) * 4;
  if (z == 2) {                            // plain convert, no transpose
#pragma unroll
    for (int i = 0; i < 4; ++i) {
      const size_t idx = (size_t)(r0 + ty + i) * C + (c0 + tx);
      wvB[idx] = f2bf(in[idx]);
    }
    return;
  }
#pragma unroll
  for (int i = 0; i < 4; ++i)
    tl[ty + i][tx] = in[(size_t)(r0 + ty + i) * C + (c0 + tx)];
  __syncthreads();
  if (z < 2) {
    unsigned char* o = wqkT8 + (size_t)z * D_INNER * D_MODEL;
#pragma unroll
    for (int i = 0; i < 4; ++i)
      o[(size_t)(c0 + ty + i) * R + (r0 + tx)] = f2fp8(tl[tx][ty + i]);
  } else {
#pragma unroll
    for (int i = 0; i < 4; ++i)
      woT[(size_t)(c0 + ty + i) * R + (r0 + tx)] = f2bf(tl[tx][ty + i]);
  }
}

// ---------------------------------------------------------------------------
extern "C" void kernel_launch(void* const* d_in, const int* in_sizes, int n_in,
                              void* d_out, int out_size, void* d_ws, size_t ws_size,
                              hipStream_t stream) {
  const float* x  = (const float*)d_in[0];
  const float* Wq = (const float*)d_in[1];
  const float* bq = (const float*)d_in[2];
  const float* Wk = (const float*)d_in[3];
  const float* bk = (const float*)d_in[4];
  const float* Wv = (const float*)d_in[5];
  const float* bv = (const float*)d_in[6];
  const float* Wo = (const float*)d_in[7];
  const float* bo = (const float*)d_in[8];
  float* out = (float*)d_out;

  // workspace layout
  short* xb    = (short*)d_ws;                          // bf16 [8192][1024] 16MB
  short* wvB   = xb    + (size_t)MTOT * D_MODEL;        // bf16 [1024][2048] 4MB
  short* woT   = wvB   + (size_t)D_MODEL * D_INNER;     // bf16 [1024][2048] 4MB
  short* wfT   = woT   + (size_t)D_MODEL * D_INNER;     // bf16 [1024][1024] 2MB
  short* Sc    = wfT   + (size_t)D_MODEL * D_MODEL;     // bf16 [4][2048][2048] 32MB
  short* w2T   = Sc    + (size_t)NBATCH * SEQ * SEQ;    // bf16 [4][1024][2048] 16MB
  unsigned char* x8    = (unsigned char*)(w2T + (size_t)NBATCH * D_MODEL * SEQ); // fp8 8MB
  unsigned char* wqkT8 = x8    + (size_t)MTOT * D_MODEL;   // fp8 [4096][1024] 4MB
  unsigned char* Qm8   = wqkT8 + (size_t)2 * D_INNER * D_MODEL; // fp8 [8192][2048] 16MB
  unsigned char* Km8   = Qm8   + (size_t)MTOT * D_INNER;        // fp8 16MB
  float* den_part      = (float*)(Km8 + (size_t)MTOT * D_INNER); // f32 [32][8192] 1MB
  float* bfuse         = den_part + (size_t)32 * MTOT;           // f32 [1024] 4KB

  dim3 b256(256);
  k_cvt<<<2048, b256, 0, stream>>>(x, xb, x8, MTOT * D_MODEL / 4);
  k_transposeAll<<<dim3(2048, 1, 4), b256, 0, stream>>>(Wq, Wk, Wv, Wo, wqkT8, wvB, woT);

  k_bfuse<<<4, b256, 0, stream>>>(bv, Wo, bfuse);
  k_wfuse<<<dim3(8, 8), b256, 0, stream>>>(wvB, woT, wfT);

  k_proj_qk8<<<dim3(32, 64), b256, 0, stream>>>(x8, wqkT8, bq, bk, Qm8, Km8);
  k_qkt8<<<dim3(136, NBATCH), b256, 0, stream>>>(Qm8, Km8, Sc, den_part);

  k_w2<<<dim3(8, 64), b256, 0, stream>>>(xb, wfT, bfuse, w2T);
  k_sv<<<dim3(8, 16, NBATCH), b256, 0, stream>>>(Sc, w2T, den_part, bo, out);
}

// Round 13
// 263.560 us; speedup vs baseline: 1.1586x; 1.1586x over previous
//
#include <hip/hip_runtime.h>
#include <hip/hip_bf16.h>

// ---------------------------------------------------------------------------
// LinearAttentionBlock: Q=phi(xWq+bq), K=phi(xWk+bk), V=xWv+bv
// scores = tril(Q K^T); out = ((scores V) / (rowsum+eps)) Wo + bo
// Algebra (r11+r12):  W2 = V Wo = x(WvWo) + bvWo ;  out = (tril(S) W2)/d + bo
// r13: k_bfuse parallelized (was 4 blocks / 74 us latency-bound -> 1024
// blocks, block-per-o reduction, ~4 us). Everything else identical to r12.
// Score path (QK-proj, QK^T): fp8 e4m3 via v_mfma_f32_16x16x128_f8f6f4.
// bf16 GEMMs: 16x16x32 core, 2-phase 128x128 tile, swizzled LDS.
// ---------------------------------------------------------------------------

#define D_MODEL 1024
#define D_INNER 2048
#define SEQ     2048
#define NBATCH  4
#define MTOT    (NBATCH * SEQ)   // 8192

typedef __attribute__((ext_vector_type(8))) __bf16 bf16x8;
typedef __attribute__((ext_vector_type(4))) float  f32x4;
typedef __attribute__((ext_vector_type(8))) short  short8v;
typedef __attribute__((ext_vector_type(4))) int    int4v;
typedef __attribute__((ext_vector_type(8))) int    int8v;

__device__ __forceinline__ short f2bf(float f) {      // RNE f32 -> bf16 bits
  union { float f; unsigned u; } x; x.f = f;
  unsigned r = x.u + 0x7fffu + ((x.u >> 16) & 1u);
  return (short)(r >> 16);
}
__device__ __forceinline__ float bf2f(short s) {
  union { unsigned u; float f; } x; x.u = ((unsigned)(unsigned short)s) << 16;
  return x.f;
}

// RNE f32 -> OCP e4m3fn (saturate to 448).
__device__ __forceinline__ unsigned char f2fp8(float f) {
  union { float f; unsigned u; } x; x.f = f;
  const unsigned s = (x.u >> 24) & 0x80u;
  const unsigned a = x.u & 0x7fffffffu;
  if (a >= 0x43E00000u) return (unsigned char)(s | 0x7Eu);   // >= 448 -> sat
  if (a < 0x3C800000u) {                                     // < 2^-6: subnormal
    union { float f; unsigned u; } y; y.u = a;
    const int mi = (int)rintf(y.f * 512.0f);                 // RNE, 0..8
    return (unsigned char)(s | (unsigned)mi);                // mi==8 -> 0x08 = 2^-6
  }
  const unsigned r = a + 0x7FFFFu + ((a >> 20) & 1u);        // RNE at 20 bits
  const unsigned E = (r >> 23) - 120u;                       // e4m3 exp field
  return (unsigned char)(s | (E << 3) | ((r >> 20) & 7u));
}

typedef const void __attribute__((address_space(1)))* as1cv;
typedef void __attribute__((address_space(3)))* as3v;

__device__ __forceinline__ void gload_lds16(const void* g, void* l) {
  __builtin_amdgcn_global_load_lds((as1cv)g, (as3v)l, 16, 0, 0);
}

__device__ __forceinline__ f32x4 mfma16(bf16x8 a, bf16x8 b, f32x4 c) {
  return __builtin_amdgcn_mfma_f32_16x16x32_bf16(a, b, c, 0, 0, 0);
}

// fp8 e4m3 x e4m3, K=128 (non-scaled f8f6f4; cbsz/blgp default 0 = fp8,fp8)
__device__ __forceinline__ f32x4 mfma_fp8(int8v a, int8v b, f32x4 c) {
  asm("v_mfma_f32_16x16x128_f8f6f4 %0, %1, %2, %0"
      : "+v"(c) : "v"(a), "v"(b));
  return c;
}

// ====================== bf16 GEMM core (16x16x32) ==========================
// LDS tile [128 rows][32 cols] bf16, 64B rows; slot ^= (row>>1)&3 swizzle.
__device__ __forceinline__ void gemm_pipe(const short* __restrict__ A, int lda, int aRowBase,
                                          const short* __restrict__ B, int ldb, int bRowBase,
                                          int k0, int k1, short* smem, f32x4 acc[4][4]) {
  const int t    = threadIdx.x;
  const int lane = t & 63, wid = t >> 6;
  const int wr = wid >> 1, wc = wid & 1;
  const int lrow = lane & 15, kblk = lane >> 4;

  const int r0 = t >> 2;
  const int sc = ((t & 3) ^ ((t >> 3) & 3)) * 8;      // pre-swizzled col
  const short* pA = A + (size_t)(aRowBase + r0) * lda + (k0 + sc);
  const short* pB = B + (size_t)(bRowBase + r0) * ldb + (k0 + sc);
  const size_t rA = (size_t)64 * lda;
  const size_t rB = (size_t)64 * ldb;

  int aoff[4], boff[4];
#pragma unroll
  for (int m = 0; m < 4; ++m) {
    const int row = wr * 64 + m * 16 + lrow;
    aoff[m] = (row * 64 + kblk * 16) ^ (((row >> 1) & 3) << 4);
  }
#pragma unroll
  for (int n = 0; n < 4; ++n) {
    const int row = wc * 64 + n * 16 + lrow;
    boff[n] = (row * 64 + kblk * 16) ^ (((row >> 1) & 3) << 4);
  }
  const char* cs = (const char*)smem;

#define STG(bufShorts) do {                                                    \
    gload_lds16(pA, smem + (bufShorts) + t * 8);                               \
    gload_lds16(pA + rA, smem + (bufShorts) + 2048 + t * 8);                   \
    gload_lds16(pB, smem + (bufShorts) + 4096 + t * 8);                        \
    gload_lds16(pB + rB, smem + (bufShorts) + 6144 + t * 8);                   \
    pA += 32; pB += 32;                                                        \
  } while (0)

#define CSTEP(bufBytes) do {                                                   \
    bf16x8 a[4], b[4];                                                         \
    _Pragma("unroll") for (int m = 0; m < 4; ++m)                              \
      a[m] = *(const bf16x8*)(cs + (bufBytes) + aoff[m]);                      \
    _Pragma("unroll") for (int n = 0; n < 4; ++n)                              \
      b[n] = *(const bf16x8*)(cs + (bufBytes) + 8192 + boff[n]);               \
    _Pragma("unroll") for (int m = 0; m < 4; ++m)                              \
      _Pragma("unroll") for (int n = 0; n < 4; ++n)                            \
        acc[m][n] = mfma16(a[m], b[n], acc[m][n]);                             \
  } while (0)

  STG(0);
  __syncthreads();
  for (int k = k0; k < k1; k += 64) {
    if (k + 32 < k1) STG(8192);
    CSTEP(0);
    __syncthreads();
    if (k + 64 < k1) STG(0);
    CSTEP(16384);
    __syncthreads();
  }
#undef STG
#undef CSTEP
}

// ============================ fp8 GEMM core ================================
// A[M,K] row-major fp8, B[N,K] row-major fp8; (k1-k0) multiple of 256.
// LDS tile [128 rows][128 B], 8 x 16B slots/row; slot ^= row&7 swizzle.
// Buffers: A0@0 B0@16K A1@32K B1@48K (64 KB total).
__device__ __forceinline__ void gemm_pipe8(const unsigned char* __restrict__ A, int lda, int aRowBase,
                                           const unsigned char* __restrict__ B, int ldb, int bRowBase,
                                           int k0, int k1, char* smem, f32x4 acc[4][4]) {
  const int t    = threadIdx.x;
  const int lane = t & 63, wid = t >> 6;
  const int wr = wid >> 1, wc = wid & 1;
  const int lrow = lane & 15, kblk = lane >> 4;

  const int srow = t >> 3;                              // 0..31
  const int scol = (((t & 7) ^ ((t >> 3) & 7)) << 4);   // pre-swizzled byte col
  const unsigned char* pA = A + (size_t)(aRowBase + srow) * lda + (k0 + scol);
  const unsigned char* pB = B + (size_t)(bRowBase + srow) * ldb + (k0 + scol);

  int aoff[4][2], boff[4][2];
#pragma unroll
  for (int m = 0; m < 4; ++m) {
    const int row = wr * 64 + m * 16 + lrow;
#pragma unroll
    for (int j = 0; j < 2; ++j)
      aoff[m][j] = row * 128 + (((kblk * 2 + j) ^ (row & 7)) << 4);
  }
#pragma unroll
  for (int n = 0; n < 4; ++n) {
    const int row = wc * 64 + n * 16 + lrow;
#pragma unroll
    for (int j = 0; j < 2; ++j)
      boff[n][j] = row * 128 + (((kblk * 2 + j) ^ (row & 7)) << 4);
  }

#define STG8(bufB) do {                                                        \
    _Pragma("unroll") for (int i = 0; i < 4; ++i) {                            \
      gload_lds16(pA + (size_t)(32 * i) * lda, smem + (bufB) + i * 4096 + t * 16);      \
      gload_lds16(pB + (size_t)(32 * i) * ldb, smem + (bufB) + 16384 + i * 4096 + t * 16); \
    }                                                                          \
    pA += 128; pB += 128;                                                      \
  } while (0)

#define CSTEP8(bufB) do {                                                      \
    int8v a[4], b[4];                                                          \
    _Pragma("unroll") for (int m = 0; m < 4; ++m)                              \
      _Pragma("unroll") for (int j = 0; j < 2; ++j)                            \
        ((int4v*)&a[m])[j] = *(const int4v*)(smem + (bufB) + aoff[m][j]);      \
    _Pragma("unroll") for (int n = 0; n < 4; ++n)                              \
      _Pragma("unroll") for (int j = 0; j < 2; ++j)                            \
        ((int4v*)&b[n])[j] = *(const int4v*)(smem + (bufB) + 16384 + boff[n][j]); \
    _Pragma("unroll") for (int m = 0; m < 4; ++m)                              \
      _Pragma("unroll") for (int n = 0; n < 4; ++n)                            \
        acc[m][n] = mfma_fp8(a[m], b[n], acc[m][n]);                           \
  } while (0)

  STG8(0);
  __syncthreads();
  for (int k = k0; k < k1; k += 256) {
    if (k + 128 < k1) STG8(32768);
    CSTEP8(0);
    __syncthreads();
    if (k + 256 < k1) STG8(0);
    CSTEP8(32768);
    __syncthreads();
  }
#undef STG8
#undef CSTEP8
}

#define GEMM_PRE                                           \
  __shared__ __align__(16) short smem[4 * 4096];           \
  f32x4 acc[4][4];                                         \
  _Pragma("unroll")                                        \
  for (int m = 0; m < 4; ++m)                              \
    _Pragma("unroll")                                      \
    for (int n = 0; n < 4; ++n) acc[m][n] = (f32x4){0.f, 0.f, 0.f, 0.f};

#define GEMM_PRE8                                          \
  __shared__ __align__(16) char smem8[65536];              \
  f32x4 acc[4][4];                                         \
  _Pragma("unroll")                                        \
  for (int m = 0; m < 4; ++m)                              \
    _Pragma("unroll")                                      \
    for (int n = 0; n < 4; ++n) acc[m][n] = (f32x4){0.f, 0.f, 0.f, 0.f};

#define EPILOG_VARS                                        \
  const int lane = threadIdx.x & 63;                       \
  const int wid  = threadIdx.x >> 6;                       \
  const int wr = wid >> 1, wc = wid & 1;                   \
  const int lrow = lane & 15, kblk = lane >> 4;

// Shared epilogue helper: transpose 128x128 bf16 tile through swizzled LDS
// (physical byte = cl*256 + ((rl*2)^((cl&7)<<5))), then 16B-coalesced stores.
__device__ __forceinline__ void retile_store(const short* smem, short* dst0, int ldd) {
  const int er  = threadIdx.x >> 1;                 // transposed-row 0..127
  const int hf  = threadIdx.x & 1;
  short* dst = dst0 + (size_t)er * ldd + hf * 64;
#pragma unroll
  for (int i = 0; i < 8; ++i) {                     // 8 x 16B = 64 elems
    int byte = er * 256 + hf * 128 + i * 16;
    byte ^= (er & 7) << 5;
    ((short8v*)dst)[i] = *(const short8v*)((const char*)smem + byte);
  }
}

// ---- fp8 Q/K projection: N = 4096 (Q | K), phi epilogue, fp8 out ----------
__global__ __launch_bounds__(256) void k_proj_qk8(const unsigned char* __restrict__ X8,
                                                  const unsigned char* __restrict__ WT8,
                                                  const float* __restrict__ bq,
                                                  const float* __restrict__ bk,
                                                  unsigned char* __restrict__ Qm8,
                                                  unsigned char* __restrict__ Km8) {
  GEMM_PRE8
  const int blockM = blockIdx.y * 128;
  const int blockN = blockIdx.x * 128;     // [0, 4096)
  gemm_pipe8(X8, D_MODEL, blockM, WT8, D_MODEL, blockN, 0, D_MODEL, smem8, acc);
  EPILOG_VARS
  const int seg = blockN >> 11;            // 0=Q 1=K
  const float* bias = (seg == 0) ? bq : bk;
  unsigned char* dst = (seg == 0) ? Qm8 : Km8;
#pragma unroll
  for (int m = 0; m < 4; ++m)
#pragma unroll
    for (int n = 0; n < 4; ++n) {
      const int e = (blockN & 2047) + wc * 64 + n * 16 + lrow;
      const float bvv = bias[e];
#pragma unroll
      for (int j = 0; j < 4; ++j) {
        const int row = blockM + wr * 64 + m * 16 + kblk * 4 + j;  // token
        float v = acc[m][n][j] + bvv;
        v = (v > 0.f) ? (v + 1.f) : __expf(v);      // elu(x)+1
        dst[(size_t)row * D_INNER + e] = f2fp8(v);
      }
    }
}

// ---- Wfuse = Wv Wo, written transposed: wfT[o][m], no bias ----------------
__global__ __launch_bounds__(256) void k_wfuse(const short* __restrict__ WvB,
                                               const short* __restrict__ WoT,
                                               short* __restrict__ wfT) {
  GEMM_PRE
  const int blockM = blockIdx.y * 128;     // m (d_model row of Wv)
  const int blockN = blockIdx.x * 128;     // o
  gemm_pipe(WvB, D_INNER, blockM, WoT, D_INNER, blockN, 0, D_INNER, smem, acc);
  EPILOG_VARS
#pragma unroll
  for (int m = 0; m < 4; ++m)
#pragma unroll
    for (int n = 0; n < 4; ++n) {
      const int cl = wc * 64 + n * 16 + lrow;       // o-local
#pragma unroll
      for (int j = 0; j < 4; ++j) {
        const int rl = wr * 64 + m * 16 + kblk * 4 + j;  // m-local
        int byte = cl * 256 + rl * 2;
        byte ^= (cl & 7) << 5;
        *(short*)((char*)smem + byte) = f2bf(acc[m][n][j]);
      }
    }
  __syncthreads();
  retile_store(smem, wfT + (size_t)blockN * D_MODEL + blockM, D_MODEL);
}

// ---- bfuse[o] = sum_e bv[e] * Wo[e][o]; block-per-o reduction (r13) -------
__global__ __launch_bounds__(256) void k_bfuse(const float* __restrict__ bv,
                                               const float* __restrict__ Wo,
                                               float* __restrict__ bfuse) {
  const int o = blockIdx.x;                         // 0..1023
  const int t = threadIdx.x;
  float s = 0.f;
#pragma unroll
  for (int e = t; e < D_INNER; e += 256)
    s += bv[e] * Wo[(size_t)e * D_MODEL + o];
#pragma unroll
  for (int off = 32; off >= 1; off >>= 1) s += __shfl_down(s, off, 64);
  __shared__ float ws[4];
  if ((t & 63) == 0) ws[t >> 6] = s;
  __syncthreads();
  if (t == 0) bfuse[o] = ws[0] + ws[1] + ws[2] + ws[3];
}

// ---- W2 = x Wfuse + bfuse, written transposed per batch: w2T[b][o][m] -----
__global__ __launch_bounds__(256) void k_w2(const short* __restrict__ X,
                                            const short* __restrict__ WfT,
                                            const float* __restrict__ bfuse,
                                            short* __restrict__ w2T) {
  GEMM_PRE
  const int blockM = blockIdx.y * 128;     // token (global)
  const int blockN = blockIdx.x * 128;     // o in [0, 1024)
  gemm_pipe(X, D_MODEL, blockM, WfT, D_MODEL, blockN, 0, D_MODEL, smem, acc);
  EPILOG_VARS
#pragma unroll
  for (int m = 0; m < 4; ++m)
#pragma unroll
    for (int n = 0; n < 4; ++n) {
      const int cl = wc * 64 + n * 16 + lrow;       // o-local
      const float bvv = bfuse[blockN + cl];
#pragma unroll
      for (int j = 0; j < 4; ++j) {
        const int rl = wr * 64 + m * 16 + kblk * 4 + j;  // token-local
        int byte = cl * 256 + rl * 2;
        byte ^= (cl & 7) << 5;
        *(short*)((char*)smem + byte) = f2bf(acc[m][n][j] + bvv);
      }
    }
  __syncthreads();
  const int b   = blockM >> 11;                     // batch
  const int mm0 = blockM & 2047;                    // token base in batch
  retile_store(smem, w2T + ((size_t)b * D_MODEL + blockN) * SEQ + mm0, SEQ);
}

// ---- scores = tril(Q K^T) in fp8, bf16 S out + row-sum partials -----------
__global__ __launch_bounds__(256) void k_qkt8(const unsigned char* __restrict__ Q8,
                                              const unsigned char* __restrict__ K8,
                                              short* __restrict__ S,
                                              float* __restrict__ den_part) {
  const int b = blockIdx.y;
  const int t = blockIdx.x;                // 0..135 -> (ib, jb<=ib)
  int ib = (int)((-1.0f + sqrtf(8.0f * (float)t + 1.0f)) * 0.5f);
  while ((ib + 1) * (ib + 2) / 2 <= t) ++ib;
  while (ib * (ib + 1) / 2 > t) --ib;
  const int jb = t - ib * (ib + 1) / 2;
  GEMM_PRE8
  short* Sb = S + (size_t)b * SEQ * SEQ;
  gemm_pipe8(Q8 + (size_t)b * SEQ * D_INNER, D_INNER, ib * 128,
             K8 + (size_t)b * SEQ * D_INNER, D_INNER, jb * 128,
             0, D_INNER, smem8, acc);
  EPILOG_VARS
  const bool diag = (jb == ib);
  float sums[4][4];
#pragma unroll
  for (int m = 0; m < 4; ++m)
#pragma unroll
    for (int j = 0; j < 4; ++j) sums[m][j] = 0.f;
#pragma unroll
  for (int m = 0; m < 4; ++m)
#pragma unroll
    for (int n = 0; n < 4; ++n) {
      const int col = jb * 128 + wc * 64 + n * 16 + lrow;       // j
#pragma unroll
      for (int j = 0; j < 4; ++j) {
        const int row = ib * 128 + wr * 64 + m * 16 + kblk * 4 + j;  // i
        float v = acc[m][n][j];
        if (diag && col > row) v = 0.f;
        const short bs = f2bf(v);
        Sb[(size_t)row * SEQ + col] = bs;
        sums[m][j] += bf2f(bs);            // sum what we stored (consistency)
      }
    }
#pragma unroll
  for (int m = 0; m < 4; ++m)
#pragma unroll
    for (int j = 0; j < 4; ++j) {
      float red = sums[m][j];
      red += __shfl_xor(red, 1, 64);
      red += __shfl_xor(red, 2, 64);
      red += __shfl_xor(red, 4, 64);
      red += __shfl_xor(red, 8, 64);
      if (lrow == 0) {
        const int rloc = wr * 64 + m * 16 + kblk * 4 + j;
        den_part[(size_t)(2 * jb + wc) * MTOT + b * SEQ + ib * 128 + rloc] = red;
      }
    }
}

// ---- out = (tril(S) W2)/d + bo  (fp32 out); K truncated; heavy ib first ---
__global__ __launch_bounds__(256) void k_sv(const short* __restrict__ S,
                                            const short* __restrict__ W2T,
                                            const float* __restrict__ den_part,
                                            const float* __restrict__ bo,
                                            float* __restrict__ out) {
  const int b = blockIdx.z;
  const int ib = 15 - blockIdx.y;          // heavy blocks dispatched first
  const int eb = blockIdx.x;               // o-tile 0..7
  __shared__ float dnm[128];
  {
    const int t = threadIdx.x;
    if (t < 128) {
      float s = 1e-6f;
      const int nv = 2 * (ib + 1);
      const float* dp = den_part + b * SEQ + ib * 128 + t;
      for (int q = 0; q < nv; ++q) s += dp[(size_t)q * MTOT];
      dnm[t] = 1.0f / s;
    }
  }
  GEMM_PRE
  gemm_pipe(S + (size_t)b * SEQ * SEQ, SEQ, ib * 128,
            W2T + (size_t)b * (size_t)D_MODEL * SEQ, SEQ, eb * 128,
            0, (ib + 1) * 128, smem, acc);  // internal barriers order dnm too
  EPILOG_VARS
  const int blockM = ib * 128;
#pragma unroll
  for (int m = 0; m < 4; ++m)
#pragma unroll
    for (int j = 0; j < 4; ++j) {
      const int rloc = wr * 64 + m * 16 + kblk * 4 + j;
      const int row = blockM + rloc;                 // token in batch
      const float rcp = dnm[rloc];
#pragma unroll
      for (int n = 0; n < 4; ++n) {
        const int col = eb * 128 + wc * 64 + n * 16 + lrow;      // o
        out[((size_t)(b * SEQ + row)) * D_MODEL + col] = acc[m][n][j] * rcp + bo[col];
      }
    }
}

// ---- converts: x -> bf16 (W2 path) + fp8 (score path) ---------------------
__global__ void k_cvt(const float* __restrict__ in, short* __restrict__ outb,
                      unsigned char* __restrict__ out8, int n4) {
  int i = blockIdx.x * blockDim.x + threadIdx.x;
  const int stride = gridDim.x * blockDim.x;
  for (; i < n4; i += stride) {
    float4 v = ((const float4*)in)[i];
    short4 o;
    o.x = f2bf(v.x); o.y = f2bf(v.y); o.z = f2bf(v.z); o.w = f2bf(v.w);
    ((short4*)outb)[i] = o;
    uchar4 q;
    q.x = f2fp8(v.x); q.y = f2fp8(v.y); q.z = f2fp8(v.z); q.w = f2fp8(v.w);
    ((uchar4*)out8)[i] = q;
  }
}

// weight prep in one launch:
// z=0,1: Wq/Wk [1024][2048] -> fp8 TRANSPOSED [2048][1024] into wqkT8
// z=2:   Wv    [1024][2048] -> bf16 same-layout convert (WvB, A-operand)
// z=3:   Wo    [2048][1024] -> bf16 TRANSPOSED [1024][2048] (woT)
__global__ __launch_bounds__(256) void k_transposeAll(const float* __restrict__ w0,
                                                      const float* __restrict__ w1,
                                                      const float* __restrict__ w2,
                                                      const float* __restrict__ w3,
                                                      unsigned char* __restrict__ wqkT8,
                                                      short* __restrict__ wvB,
                                                      short* __restrict__ woT) {
  __shared__ float tl[32][33];
  const int z = blockIdx.z;
  const float* in = (z == 0) ? w0 : (z == 1) ? w1 : (z == 2) ? w2 : w3;
  const int R = (z < 3) ? 1024 : 2048;     // in rows
  const int C = (z < 3) ? 2048 : 1024;     // in cols
  const int nbx = C >> 5;
  const int c0 = (blockIdx.x % nbx) * 32, r0 = (blockIdx.x / nbx) * 32;
  const int tx = threadIdx.x & 31, ty = (threadIdx.x >> 5) * 4;
  if (z == 2) {                            // plain convert, no transpose
#pragma unroll
    for (int i = 0; i < 4; ++i) {
      const size_t idx = (size_t)(r0 + ty + i) * C + (c0 + tx);
      wvB[idx] = f2bf(in[idx]);
    }
    return;
  }
#pragma unroll
  for (int i = 0; i < 4; ++i)
    tl[ty + i][tx] = in[(size_t)(r0 + ty + i) * C + (c0 + tx)];
  __syncthreads();
  if (z < 2) {
    unsigned char* o = wqkT8 + (size_t)z * D_INNER * D_MODEL;
#pragma unroll
    for (int i = 0; i < 4; ++i)
      o[(size_t)(c0 + ty + i) * R + (r0 + tx)] = f2fp8(tl[tx][ty + i]);
  } else {
#pragma unroll
    for (int i = 0; i < 4; ++i)
      woT[(size_t)(c0 + ty + i) * R + (r0 + tx)] = f2bf(tl[tx][ty + i]);
  }
}

// ---------------------------------------------------------------------------
extern "C" void kernel_launch(void* const* d_in, const int* in_sizes, int n_in,
                              void* d_out, int out_size, void* d_ws, size_t ws_size,
                              hipStream_t stream) {
  const float* x  = (const float*)d_in[0];
  const float* Wq = (const float*)d_in[1];
  const float* bq = (const float*)d_in[2];
  const float* Wk = (const float*)d_in[3];
  const float* bk = (const float*)d_in[4];
  const float* Wv = (const float*)d_in[5];
  const float* bv = (const float*)d_in[6];
  const float* Wo = (const float*)d_in[7];
  const float* bo = (const float*)d_in[8];
  float* out = (float*)d_out;

  // workspace layout
  short* xb    = (short*)d_ws;                          // bf16 [8192][1024] 16MB
  short* wvB   = xb    + (size_t)MTOT * D_MODEL;        // bf16 [1024][2048] 4MB
  short* woT   = wvB   + (size_t)D_MODEL * D_INNER;     // bf16 [1024][2048] 4MB
  short* wfT   = woT   + (size_t)D_MODEL * D_INNER;     // bf16 [1024][1024] 2MB
  short* Sc    = wfT   + (size_t)D_MODEL * D_MODEL;     // bf16 [4][2048][2048] 32MB
  short* w2T   = Sc    + (size_t)NBATCH * SEQ * SEQ;    // bf16 [4][1024][2048] 16MB
  unsigned char* x8    = (unsigned char*)(w2T + (size_t)NBATCH * D_MODEL * SEQ); // fp8 8MB
  unsigned char* wqkT8 = x8    + (size_t)MTOT * D_MODEL;   // fp8 [4096][1024] 4MB
  unsigned char* Qm8   = wqkT8 + (size_t)2 * D_INNER * D_MODEL; // fp8 [8192][2048] 16MB
  unsigned char* Km8   = Qm8   + (size_t)MTOT * D_INNER;        // fp8 16MB
  float* den_part      = (float*)(Km8 + (size_t)MTOT * D_INNER); // f32 [32][8192] 1MB
  float* bfuse         = den_part + (size_t)32 * MTOT;           // f32 [1024] 4KB

  dim3 b256(256);
  k_cvt<<<2048, b256, 0, stream>>>(x, xb, x8, MTOT * D_MODEL / 4);
  k_transposeAll<<<dim3(2048, 1, 4), b256, 0, stream>>>(Wq, Wk, Wv, Wo, wqkT8, wvB, woT);

  k_bfuse<<<1024, b256, 0, stream>>>(bv, Wo, bfuse);
  k_wfuse<<<dim3(8, 8), b256, 0, stream>>>(wvB, woT, wfT);

  k_proj_qk8<<<dim3(32, 64), b256, 0, stream>>>(x8, wqkT8, bq, bk, Qm8, Km8);
  k_qkt8<<<dim3(136, NBATCH), b256, 0, stream>>>(Qm8, Km8, Sc, den_part);

  k_w2<<<dim3(8, 64), b256, 0, stream>>>(xb, wfT, bfuse, w2T);
  k_sv<<<dim3(8, 16, NBATCH), b256, 0, stream>>>(Sc, w2T, den_part, bo, out);
}

// Round 14
// 261.749 us; speedup vs baseline: 1.1667x; 1.0069x over previous
//
#include <hip/hip_runtime.h>
#include <hip/hip_bf16.h>

// ---------------------------------------------------------------------------
// LinearAttentionBlock: Q=phi(xWq+bq), K=phi(xWk+bk), V=xWv+bv
// scores = tril(Q K^T); out = ((scores V) / (rowsum+eps)) Wo + bo
// Algebra:  W2 = V Wo = x(WvWo) + bvWo ;  out = (tril(S) W2)/d + bo
// Score path (QK-proj, QK^T): fp8 e4m3 via v_mfma_f32_16x16x128_f8f6f4.
// r14: qkt8 -> single-buffered 32KB fp8 core (5 blocks/CU; kills the
// 544-vs-512 capacity tail of the 64KB dbuf core). proj_qk8 keeps dbuf.
// Preprocessing (cvt + 4 weight transposes + bfuse) merged into one launch.
// ---------------------------------------------------------------------------

#define D_MODEL 1024
#define D_INNER 2048
#define SEQ     2048
#define NBATCH  4
#define MTOT    (NBATCH * SEQ)   // 8192

typedef __attribute__((ext_vector_type(8))) __bf16 bf16x8;
typedef __attribute__((ext_vector_type(4))) float  f32x4;
typedef __attribute__((ext_vector_type(8))) short  short8v;
typedef __attribute__((ext_vector_type(4))) int    int4v;
typedef __attribute__((ext_vector_type(8))) int    int8v;

__device__ __forceinline__ short f2bf(float f) {      // RNE f32 -> bf16 bits
  union { float f; unsigned u; } x; x.f = f;
  unsigned r = x.u + 0x7fffu + ((x.u >> 16) & 1u);
  return (short)(r >> 16);
}
__device__ __forceinline__ float bf2f(short s) {
  union { unsigned u; float f; } x; x.u = ((unsigned)(unsigned short)s) << 16;
  return x.f;
}

// RNE f32 -> OCP e4m3fn (saturate to 448).
__device__ __forceinline__ unsigned char f2fp8(float f) {
  union { float f; unsigned u; } x; x.f = f;
  const unsigned s = (x.u >> 24) & 0x80u;
  const unsigned a = x.u & 0x7fffffffu;
  if (a >= 0x43E00000u) return (unsigned char)(s | 0x7Eu);   // >= 448 -> sat
  if (a < 0x3C800000u) {                                     // < 2^-6: subnormal
    union { float f; unsigned u; } y; y.u = a;
    const int mi = (int)rintf(y.f * 512.0f);                 // RNE, 0..8
    return (unsigned char)(s | (unsigned)mi);                // mi==8 -> 0x08 = 2^-6
  }
  const unsigned r = a + 0x7FFFFu + ((a >> 20) & 1u);        // RNE at 20 bits
  const unsigned E = (r >> 23) - 120u;                       // e4m3 exp field
  return (unsigned char)(s | (E << 3) | ((r >> 20) & 7u));
}

typedef const void __attribute__((address_space(1)))* as1cv;
typedef void __attribute__((address_space(3)))* as3v;

__device__ __forceinline__ void gload_lds16(const void* g, void* l) {
  __builtin_amdgcn_global_load_lds((as1cv)g, (as3v)l, 16, 0, 0);
}

__device__ __forceinline__ f32x4 mfma16(bf16x8 a, bf16x8 b, f32x4 c) {
  return __builtin_amdgcn_mfma_f32_16x16x32_bf16(a, b, c, 0, 0, 0);
}

// fp8 e4m3 x e4m3, K=128 (non-scaled f8f6f4; cbsz/blgp default 0 = fp8,fp8)
__device__ __forceinline__ f32x4 mfma_fp8(int8v a, int8v b, f32x4 c) {
  asm("v_mfma_f32_16x16x128_f8f6f4 %0, %1, %2, %0"
      : "+v"(c) : "v"(a), "v"(b));
  return c;
}

// ====================== bf16 GEMM core (16x16x32) ==========================
// LDS tile [128 rows][32 cols] bf16, 64B rows; slot ^= (row>>1)&3 swizzle.
__device__ __forceinline__ void gemm_pipe(const short* __restrict__ A, int lda, int aRowBase,
                                          const short* __restrict__ B, int ldb, int bRowBase,
                                          int k0, int k1, short* smem, f32x4 acc[4][4]) {
  const int t    = threadIdx.x;
  const int lane = t & 63, wid = t >> 6;
  const int wr = wid >> 1, wc = wid & 1;
  const int lrow = lane & 15, kblk = lane >> 4;

  const int r0 = t >> 2;
  const int sc = ((t & 3) ^ ((t >> 3) & 3)) * 8;      // pre-swizzled col
  const short* pA = A + (size_t)(aRowBase + r0) * lda + (k0 + sc);
  const short* pB = B + (size_t)(bRowBase + r0) * ldb + (k0 + sc);
  const size_t rA = (size_t)64 * lda;
  const size_t rB = (size_t)64 * ldb;

  int aoff[4], boff[4];
#pragma unroll
  for (int m = 0; m < 4; ++m) {
    const int row = wr * 64 + m * 16 + lrow;
    aoff[m] = (row * 64 + kblk * 16) ^ (((row >> 1) & 3) << 4);
  }
#pragma unroll
  for (int n = 0; n < 4; ++n) {
    const int row = wc * 64 + n * 16 + lrow;
    boff[n] = (row * 64 + kblk * 16) ^ (((row >> 1) & 3) << 4);
  }
  const char* cs = (const char*)smem;

#define STG(bufShorts) do {                                                    \
    gload_lds16(pA, smem + (bufShorts) + t * 8);                               \
    gload_lds16(pA + rA, smem + (bufShorts) + 2048 + t * 8);                   \
    gload_lds16(pB, smem + (bufShorts) + 4096 + t * 8);                        \
    gload_lds16(pB + rB, smem + (bufShorts) + 6144 + t * 8);                   \
    pA += 32; pB += 32;                                                        \
  } while (0)

#define CSTEP(bufBytes) do {                                                   \
    bf16x8 a[4], b[4];                                                         \
    _Pragma("unroll") for (int m = 0; m < 4; ++m)                              \
      a[m] = *(const bf16x8*)(cs + (bufBytes) + aoff[m]);                      \
    _Pragma("unroll") for (int n = 0; n < 4; ++n)                              \
      b[n] = *(const bf16x8*)(cs + (bufBytes) + 8192 + boff[n]);               \
    _Pragma("unroll") for (int m = 0; m < 4; ++m)                              \
      _Pragma("unroll") for (int n = 0; n < 4; ++n)                            \
        acc[m][n] = mfma16(a[m], b[n], acc[m][n]);                             \
  } while (0)

  STG(0);
  __syncthreads();
  for (int k = k0; k < k1; k += 64) {
    if (k + 32 < k1) STG(8192);
    CSTEP(0);
    __syncthreads();
    if (k + 64 < k1) STG(0);
    CSTEP(16384);
    __syncthreads();
  }
#undef STG
#undef CSTEP
}

// ================== fp8 GEMM core, double-buffered (64 KB) =================
// A[M,K] row-major fp8, B[N,K] row-major fp8; (k1-k0) multiple of 256.
// LDS tile [128 rows][128 B], 8 x 16B slots/row; slot ^= row&7 swizzle.
// Buffers: A0@0 B0@16K A1@32K B1@48K.
__device__ __forceinline__ void gemm_pipe8(const unsigned char* __restrict__ A, int lda, int aRowBase,
                                           const unsigned char* __restrict__ B, int ldb, int bRowBase,
                                           int k0, int k1, char* smem, f32x4 acc[4][4]) {
  const int t    = threadIdx.x;
  const int lane = t & 63, wid = t >> 6;
  const int wr = wid >> 1, wc = wid & 1;
  const int lrow = lane & 15, kblk = lane >> 4;

  const int srow = t >> 3;                              // 0..31
  const int scol = (((t & 7) ^ ((t >> 3) & 7)) << 4);   // pre-swizzled byte col
  const unsigned char* pA = A + (size_t)(aRowBase + srow) * lda + (k0 + scol);
  const unsigned char* pB = B + (size_t)(bRowBase + srow) * ldb + (k0 + scol);

  int aoff[4][2], boff[4][2];
#pragma unroll
  for (int m = 0; m < 4; ++m) {
    const int row = wr * 64 + m * 16 + lrow;
#pragma unroll
    for (int j = 0; j < 2; ++j)
      aoff[m][j] = row * 128 + (((kblk * 2 + j) ^ (row & 7)) << 4);
  }
#pragma unroll
  for (int n = 0; n < 4; ++n) {
    const int row = wc * 64 + n * 16 + lrow;
#pragma unroll
    for (int j = 0; j < 2; ++j)
      boff[n][j] = row * 128 + (((kblk * 2 + j) ^ (row & 7)) << 4);
  }

#define STG8(bufB) do {                                                        \
    _Pragma("unroll") for (int i = 0; i < 4; ++i) {                            \
      gload_lds16(pA + (size_t)(32 * i) * lda, smem + (bufB) + i * 4096 + t * 16);      \
      gload_lds16(pB + (size_t)(32 * i) * ldb, smem + (bufB) + 16384 + i * 4096 + t * 16); \
    }                                                                          \
    pA += 128; pB += 128;                                                      \
  } while (0)

#define CSTEP8(bufB) do {                                                      \
    int8v a[4], b[4];                                                          \
    _Pragma("unroll") for (int m = 0; m < 4; ++m)                              \
      _Pragma("unroll") for (int j = 0; j < 2; ++j)                            \
        ((int4v*)&a[m])[j] = *(const int4v*)(smem + (bufB) + aoff[m][j]);      \
    _Pragma("unroll") for (int n = 0; n < 4; ++n)                              \
      _Pragma("unroll") for (int j = 0; j < 2; ++j)                            \
        ((int4v*)&b[n])[j] = *(const int4v*)(smem + (bufB) + 16384 + boff[n][j]); \
    _Pragma("unroll") for (int m = 0; m < 4; ++m)                              \
      _Pragma("unroll") for (int n = 0; n < 4; ++n)                            \
        acc[m][n] = mfma_fp8(a[m], b[n], acc[m][n]);                           \
  } while (0)

  STG8(0);
  __syncthreads();
  for (int k = k0; k < k1; k += 256) {
    if (k + 128 < k1) STG8(32768);
    CSTEP8(0);
    __syncthreads();
    if (k + 256 < k1) STG8(0);
    CSTEP8(32768);
    __syncthreads();
  }
#undef STG8
#undef CSTEP8
}

// ================== fp8 GEMM core, single-buffered (32 KB) =================
// Same tile/swizzle as gemm_pipe8, one buffer (A@0, B@16K), BK=128.
// 5 blocks/CU occupancy; used where block-count vs capacity tails matter.
__device__ __forceinline__ void gemm_pipe8s(const unsigned char* __restrict__ A, int lda, int aRowBase,
                                            const unsigned char* __restrict__ B, int ldb, int bRowBase,
                                            int k0, int k1, char* smem, f32x4 acc[4][4]) {
  const int t    = threadIdx.x;
  const int lane = t & 63, wid = t >> 6;
  const int wr = wid >> 1, wc = wid & 1;
  const int lrow = lane & 15, kblk = lane >> 4;

  const int srow = t >> 3;                              // 0..31
  const int scol = (((t & 7) ^ ((t >> 3) & 7)) << 4);   // pre-swizzled byte col
  const unsigned char* pA = A + (size_t)(aRowBase + srow) * lda + (k0 + scol);
  const unsigned char* pB = B + (size_t)(bRowBase + srow) * ldb + (k0 + scol);

  int aoff[4][2], boff[4][2];
#pragma unroll
  for (int m = 0; m < 4; ++m) {
    const int row = wr * 64 + m * 16 + lrow;
#pragma unroll
    for (int j = 0; j < 2; ++j)
      aoff[m][j] = row * 128 + (((kblk * 2 + j) ^ (row & 7)) << 4);
  }
#pragma unroll
  for (int n = 0; n < 4; ++n) {
    const int row = wc * 64 + n * 16 + lrow;
#pragma unroll
    for (int j = 0; j < 2; ++j)
      boff[n][j] = row * 128 + (((kblk * 2 + j) ^ (row & 7)) << 4);
  }

  for (int k = k0; k < k1; k += 128) {
#pragma unroll
    for (int i = 0; i < 4; ++i) {
      gload_lds16(pA + (size_t)(32 * i) * lda, smem + i * 4096 + t * 16);
      gload_lds16(pB + (size_t)(32 * i) * ldb, smem + 16384 + i * 4096 + t * 16);
    }
    pA += 128; pB += 128;
    __syncthreads();                       // drain vmcnt + barrier
    int8v a[4], b[4];
#pragma unroll
    for (int m = 0; m < 4; ++m)
#pragma unroll
      for (int j = 0; j < 2; ++j)
        ((int4v*)&a[m])[j] = *(const int4v*)(smem + aoff[m][j]);
#pragma unroll
    for (int n = 0; n < 4; ++n)
#pragma unroll
      for (int j = 0; j < 2; ++j)
        ((int4v*)&b[n])[j] = *(const int4v*)(smem + 16384 + boff[n][j]);
#pragma unroll
    for (int m = 0; m < 4; ++m)
#pragma unroll
      for (int n = 0; n < 4; ++n)
        acc[m][n] = mfma_fp8(a[m], b[n], acc[m][n]);
    __syncthreads();                       // before next-tile overwrite
  }
}

#define GEMM_PRE                                           \
  __shared__ __align__(16) short smem[4 * 4096];           \
  f32x4 acc[4][4];                                         \
  _Pragma("unroll")                                        \
  for (int m = 0; m < 4; ++m)                              \
    _Pragma("unroll")                                      \
    for (int n = 0; n < 4; ++n) acc[m][n] = (f32x4){0.f, 0.f, 0.f, 0.f};

#define GEMM_PRE8                                          \
  __shared__ __align__(16) char smem8[65536];              \
  f32x4 acc[4][4];                                         \
  _Pragma("unroll")                                        \
  for (int m = 0; m < 4; ++m)                              \
    _Pragma("unroll")                                      \
    for (int n = 0; n < 4; ++n) acc[m][n] = (f32x4){0.f, 0.f, 0.f, 0.f};

#define GEMM_PRE8S                                         \
  __shared__ __align__(16) char smem8[32768];              \
  f32x4 acc[4][4];                                         \
  _Pragma("unroll")                                        \
  for (int m = 0; m < 4; ++m)                              \
    _Pragma("unroll")                                      \
    for (int n = 0; n < 4; ++n) acc[m][n] = (f32x4){0.f, 0.f, 0.f, 0.f};

#define EPILOG_VARS                                        \
  const int lane = threadIdx.x & 63;                       \
  const int wid  = threadIdx.x >> 6;                       \
  const int wr = wid >> 1, wc = wid & 1;                   \
  const int lrow = lane & 15, kblk = lane >> 4;

// Transpose 128x128 bf16 tile through swizzled LDS then coalesced stores.
__device__ __forceinline__ void retile_store(const short* smem, short* dst0, int ldd) {
  const int er  = threadIdx.x >> 1;                 // transposed-row 0..127
  const int hf  = threadIdx.x & 1;
  short* dst = dst0 + (size_t)er * ldd + hf * 64;
#pragma unroll
  for (int i = 0; i < 8; ++i) {                     // 8 x 16B = 64 elems
    int byte = er * 256 + hf * 128 + i * 16;
    byte ^= (er & 7) << 5;
    ((short8v*)dst)[i] = *(const short8v*)((const char*)smem + byte);
  }
}

// ---- fp8 Q/K projection: N = 4096 (Q | K), phi epilogue, fp8 out ----------
__global__ __launch_bounds__(256) void k_proj_qk8(const unsigned char* __restrict__ X8,
                                                  const unsigned char* __restrict__ WT8,
                                                  const float* __restrict__ bq,
                                                  const float* __restrict__ bk,
                                                  unsigned char* __restrict__ Qm8,
                                                  unsigned char* __restrict__ Km8) {
  GEMM_PRE8
  const int blockM = blockIdx.y * 128;
  const int blockN = blockIdx.x * 128;     // [0, 4096)
  gemm_pipe8(X8, D_MODEL, blockM, WT8, D_MODEL, blockN, 0, D_MODEL, smem8, acc);
  EPILOG_VARS
  const int seg = blockN >> 11;            // 0=Q 1=K
  const float* bias = (seg == 0) ? bq : bk;
  unsigned char* dst = (seg == 0) ? Qm8 : Km8;
#pragma unroll
  for (int m = 0; m < 4; ++m)
#pragma unroll
    for (int n = 0; n < 4; ++n) {
      const int e = (blockN & 2047) + wc * 64 + n * 16 + lrow;
      const float bvv = bias[e];
#pragma unroll
      for (int j = 0; j < 4; ++j) {
        const int row = blockM + wr * 64 + m * 16 + kblk * 4 + j;  // token
        float v = acc[m][n][j] + bvv;
        v = (v > 0.f) ? (v + 1.f) : __expf(v);      // elu(x)+1
        dst[(size_t)row * D_INNER + e] = f2fp8(v);
      }
    }
}

// ---- Wfuse = Wv Wo, written transposed: wfT[o][m], no bias ----------------
__global__ __launch_bounds__(256) void k_wfuse(const short* __restrict__ WvB,
                                               const short* __restrict__ WoT,
                                               short* __restrict__ wfT) {
  GEMM_PRE
  const int blockM = blockIdx.y * 128;     // m (d_model row of Wv)
  const int blockN = blockIdx.x * 128;     // o
  gemm_pipe(WvB, D_INNER, blockM, WoT, D_INNER, blockN, 0, D_INNER, smem, acc);
  EPILOG_VARS
#pragma unroll
  for (int m = 0; m < 4; ++m)
#pragma unroll
    for (int n = 0; n < 4; ++n) {
      const int cl = wc * 64 + n * 16 + lrow;       // o-local
#pragma unroll
      for (int j = 0; j < 4; ++j) {
        const int rl = wr * 64 + m * 16 + kblk * 4 + j;  // m-local
        int byte = cl * 256 + rl * 2;
        byte ^= (cl & 7) << 5;
        *(short*)((char*)smem + byte) = f2bf(acc[m][n][j]);
      }
    }
  __syncthreads();
  retile_store(smem, wfT + (size_t)blockN * D_MODEL + blockM, D_MODEL);
}

// ---- W2 = x Wfuse + bfuse, written transposed per batch: w2T[b][o][m] -----
__global__ __launch_bounds__(256) void k_w2(const short* __restrict__ X,
                                            const short* __restrict__ WfT,
                                            const float* __restrict__ bfuse,
                                            short* __restrict__ w2T) {
  GEMM_PRE
  const int blockM = blockIdx.y * 128;     // token (global)
  const int blockN = blockIdx.x * 128;     // o in [0, 1024)
  gemm_pipe(X, D_MODEL, blockM, WfT, D_MODEL, blockN, 0, D_MODEL, smem, acc);
  EPILOG_VARS
#pragma unroll
  for (int m = 0; m < 4; ++m)
#pragma unroll
    for (int n = 0; n < 4; ++n) {
      const int cl = wc * 64 + n * 16 + lrow;       // o-local
      const float bvv = bfuse[blockN + cl];
#pragma unroll
      for (int j = 0; j < 4; ++j) {
        const int rl = wr * 64 + m * 16 + kblk * 4 + j;  // token-local
        int byte = cl * 256 + rl * 2;
        byte ^= (cl & 7) << 5;
        *(short*)((char*)smem + byte) = f2bf(acc[m][n][j] + bvv);
      }
    }
  __syncthreads();
  const int b   = blockM >> 11;                     // batch
  const int mm0 = blockM & 2047;                    // token base in batch
  retile_store(smem, w2T + ((size_t)b * D_MODEL + blockN) * SEQ + mm0, SEQ);
}

// ---- scores = tril(Q K^T) in fp8 (single-buffer core), + row-sum partials -
__global__ __launch_bounds__(256) void k_qkt8(const unsigned char* __restrict__ Q8,
                                              const unsigned char* __restrict__ K8,
                                              short* __restrict__ S,
                                              float* __restrict__ den_part) {
  const int b = blockIdx.y;
  const int t = blockIdx.x;                // 0..135 -> (ib, jb<=ib)
  int ib = (int)((-1.0f + sqrtf(8.0f * (float)t + 1.0f)) * 0.5f);
  while ((ib + 1) * (ib + 2) / 2 <= t) ++ib;
  while (ib * (ib + 1) / 2 > t) --ib;
  const int jb = t - ib * (ib + 1) / 2;
  GEMM_PRE8S
  short* Sb = S + (size_t)b * SEQ * SEQ;
  gemm_pipe8s(Q8 + (size_t)b * SEQ * D_INNER, D_INNER, ib * 128,
              K8 + (size_t)b * SEQ * D_INNER, D_INNER, jb * 128,
              0, D_INNER, smem8, acc);
  EPILOG_VARS
  const bool diag = (jb == ib);
  float sums[4][4];
#pragma unroll
  for (int m = 0; m < 4; ++m)
#pragma unroll
    for (int j = 0; j < 4; ++j) sums[m][j] = 0.f;
#pragma unroll
  for (int m = 0; m < 4; ++m)
#pragma unroll
    for (int n = 0; n < 4; ++n) {
      const int col = jb * 128 + wc * 64 + n * 16 + lrow;       // j
#pragma unroll
      for (int j = 0; j < 4; ++j) {
        const int row = ib * 128 + wr * 64 + m * 16 + kblk * 4 + j;  // i
        float v = acc[m][n][j];
        if (diag && col > row) v = 0.f;
        const short bs = f2bf(v);
        Sb[(size_t)row * SEQ + col] = bs;
        sums[m][j] += bf2f(bs);            // sum what we stored (consistency)
      }
    }
#pragma unroll
  for (int m = 0; m < 4; ++m)
#pragma unroll
    for (int j = 0; j < 4; ++j) {
      float red = sums[m][j];
      red += __shfl_xor(red, 1, 64);
      red += __shfl_xor(red, 2, 64);
      red += __shfl_xor(red, 4, 64);
      red += __shfl_xor(red, 8, 64);
      if (lrow == 0) {
        const int rloc = wr * 64 + m * 16 + kblk * 4 + j;
        den_part[(size_t)(2 * jb + wc) * MTOT + b * SEQ + ib * 128 + rloc] = red;
      }
    }
}

// ---- out = (tril(S) W2)/d + bo  (fp32 out); K truncated; heavy ib first ---
__global__ __launch_bounds__(256) void k_sv(const short* __restrict__ S,
                                            const short* __restrict__ W2T,
                                            const float* __restrict__ den_part,
                                            const float* __restrict__ bo,
                                            float* __restrict__ out) {
  const int b = blockIdx.z;
  const int ib = 15 - blockIdx.y;          // heavy blocks dispatched first
  const int eb = blockIdx.x;               // o-tile 0..7
  __shared__ float dnm[128];
  {
    const int t = threadIdx.x;
    if (t < 128) {
      float s = 1e-6f;
      const int nv = 2 * (ib + 1);
      const float* dp = den_part + b * SEQ + ib * 128 + t;
      for (int q = 0; q < nv; ++q) s += dp[(size_t)q * MTOT];
      dnm[t] = 1.0f / s;
    }
  }
  GEMM_PRE
  gemm_pipe(S + (size_t)b * SEQ * SEQ, SEQ, ib * 128,
            W2T + (size_t)b * (size_t)D_MODEL * SEQ, SEQ, eb * 128,
            0, (ib + 1) * 128, smem, acc);  // internal barriers order dnm too
  EPILOG_VARS
  const int blockM = ib * 128;
#pragma unroll
  for (int m = 0; m < 4; ++m)
#pragma unroll
    for (int j = 0; j < 4; ++j) {
      const int rloc = wr * 64 + m * 16 + kblk * 4 + j;
      const int row = blockM + rloc;                 // token in batch
      const float rcp = dnm[rloc];
#pragma unroll
      for (int n = 0; n < 4; ++n) {
        const int col = eb * 128 + wc * 64 + n * 16 + lrow;      // o
        out[((size_t)(b * SEQ + row)) * D_MODEL + col] = acc[m][n][j] * rcp + bo[col];
      }
    }
}

// ---- merged preprocessing: cvt (blocks 0..2047), weight transposes
// (2048..10239, 4 z-planes of 2048), bfuse (10240..11263) -------------------
__global__ __launch_bounds__(256) void k_pre(const float* __restrict__ x,
                                             const float* __restrict__ Wq,
                                             const float* __restrict__ Wk,
                                             const float* __restrict__ Wv,
                                             const float* __restrict__ Wo,
                                             const float* __restrict__ bv,
                                             short* __restrict__ xb,
                                             unsigned char* __restrict__ x8,
                                             unsigned char* __restrict__ wqkT8,
                                             short* __restrict__ wvB,
                                             short* __restrict__ woT,
                                             float* __restrict__ bfuse) {
  __shared__ float tl[32][33];
  __shared__ float ws[4];
  const int bid = blockIdx.x;
  if (bid < 2048) {
    // ---- x -> bf16 + fp8 (grid-stride over float4s) ----
    const int n4 = MTOT * D_MODEL / 4;
    int i = bid * 256 + threadIdx.x;
    const int stride = 2048 * 256;
    for (; i < n4; i += stride) {
      float4 v = ((const float4*)x)[i];
      short4 o;
      o.x = f2bf(v.x); o.y = f2bf(v.y); o.z = f2bf(v.z); o.w = f2bf(v.w);
      ((short4*)xb)[i] = o;
      uchar4 q;
      q.x = f2fp8(v.x); q.y = f2fp8(v.y); q.z = f2fp8(v.z); q.w = f2fp8(v.w);
      ((uchar4*)x8)[i] = q;
    }
  } else if (bid < 2048 + 4 * 2048) {
    // ---- weight prep: z=0,1 Wq/Wk -> fp8 transposed; z=2 Wv bf16 convert;
    //      z=3 Wo -> bf16 transposed ----
    const int z  = (bid - 2048) >> 11;
    const int bx = (bid - 2048) & 2047;
    const float* in = (z == 0) ? Wq : (z == 1) ? Wk : (z == 2) ? Wv : Wo;
    const int R = (z < 3) ? 1024 : 2048;
    const int C = (z < 3) ? 2048 : 1024;
    const int nbx = C >> 5;
    const int c0 = (bx % nbx) * 32, r0 = (bx / nbx) * 32;
    const int tx = threadIdx.x & 31, ty = (threadIdx.x >> 5) * 4;
    if (z == 2) {                          // plain convert, no transpose
#pragma unroll
      for (int i = 0; i < 4; ++i) {
        const size_t idx = (size_t)(r0 + ty + i) * C + (c0 + tx);
        wvB[idx] = f2bf(in[idx]);
      }
      return;
    }
#pragma unroll
    for (int i = 0; i < 4; ++i)
      tl[ty + i][tx] = in[(size_t)(r0 + ty + i) * C + (c0 + tx)];
    __syncthreads();
    if (z < 2) {
      unsigned char* o = wqkT8 + (size_t)z * D_INNER * D_MODEL;
#pragma unroll
      for (int i = 0; i < 4; ++i)
        o[(size_t)(c0 + ty + i) * R + (r0 + tx)] = f2fp8(tl[tx][ty + i]);
    } else {
#pragma unroll
      for (int i = 0; i < 4; ++i)
        woT[(size_t)(c0 + ty + i) * R + (r0 + tx)] = f2bf(tl[tx][ty + i]);
    }
  } else {
    // ---- bfuse[o] = sum_e bv[e] * Wo[e][o], block-per-o ----
    const int o = bid - (2048 + 4 * 2048);            // 0..1023
    const int t = threadIdx.x;
    float s = 0.f;
#pragma unroll
    for (int e = t; e < D_INNER; e += 256)
      s += bv[e] * Wo[(size_t)e * D_MODEL + o];
#pragma unroll
    for (int off = 32; off >= 1; off >>= 1) s += __shfl_down(s, off, 64);
    if ((t & 63) == 0) ws[t >> 6] = s;
    __syncthreads();
    if (t == 0) bfuse[o] = ws[0] + ws[1] + ws[2] + ws[3];
  }
}

// ---------------------------------------------------------------------------
extern "C" void kernel_launch(void* const* d_in, const int* in_sizes, int n_in,
                              void* d_out, int out_size, void* d_ws, size_t ws_size,
                              hipStream_t stream) {
  const float* x  = (const float*)d_in[0];
  const float* Wq = (const float*)d_in[1];
  const float* bq = (const float*)d_in[2];
  const float* Wk = (const float*)d_in[3];
  const float* bk = (const float*)d_in[4];
  const float* Wv = (const float*)d_in[5];
  const float* bv = (const float*)d_in[6];
  const float* Wo = (const float*)d_in[7];
  const float* bo = (const float*)d_in[8];
  float* out = (float*)d_out;

  // workspace layout
  short* xb    = (short*)d_ws;                          // bf16 [8192][1024] 16MB
  short* wvB   = xb    + (size_t)MTOT * D_MODEL;        // bf16 [1024][2048] 4MB
  short* woT   = wvB   + (size_t)D_MODEL * D_INNER;     // bf16 [1024][2048] 4MB
  short* wfT   = woT   + (size_t)D_MODEL * D_INNER;     // bf16 [1024][1024] 2MB
  short* Sc    = wfT   + (size_t)D_MODEL * D_MODEL;     // bf16 [4][2048][2048] 32MB
  short* w2T   = Sc    + (size_t)NBATCH * SEQ * SEQ;    // bf16 [4][1024][2048] 16MB
  unsigned char* x8    = (unsigned char*)(w2T + (size_t)NBATCH * D_MODEL * SEQ); // fp8 8MB
  unsigned char* wqkT8 = x8    + (size_t)MTOT * D_MODEL;   // fp8 [4096][1024] 4MB
  unsigned char* Qm8   = wqkT8 + (size_t)2 * D_INNER * D_MODEL; // fp8 [8192][2048] 16MB
  unsigned char* Km8   = Qm8   + (size_t)MTOT * D_INNER;        // fp8 16MB
  float* den_part      = (float*)(Km8 + (size_t)MTOT * D_INNER); // f32 [32][8192] 1MB
  float* bfuse         = den_part + (size_t)32 * MTOT;           // f32 [1024] 4KB

  dim3 b256(256);
  k_pre<<<11264, b256, 0, stream>>>(x, Wq, Wk, Wv, Wo, bv,
                                    xb, x8, wqkT8, wvB, woT, bfuse);
  k_wfuse<<<dim3(8, 8), b256, 0, stream>>>(wvB, woT, wfT);

  k_proj_qk8<<<dim3(32, 64), b256, 0, stream>>>(x8, wqkT8, bq, bk, Qm8, Km8);
  k_qkt8<<<dim3(136, NBATCH), b256, 0, stream>>>(Qm8, Km8, Sc, den_part);

  k_w2<<<dim3(8, 64), b256, 0, stream>>>(xb, wfT, bfuse, w2T);
  k_sv<<<dim3(8, 16, NBATCH), b256, 0, stream>>>(Sc, w2T, den_part, bo, out);
}